// Round 10
// baseline (534.387 us; speedup 1.0000x reference)
//
#include <hip/hip_runtime.h>
#include <hip/hip_bf16.h>
#include <hip/hip_cooperative_groups.h>

namespace cg = cooperative_groups;

#define NNODES 4096
#define NEDGES 131072
#define D_IN   768
#define D_H    256
#define NHEAD  4
#define D_HEAD 64
#define D_OUT  128
#define DEGCAP 192
#define NBLK   512
#define CONV_WIN  196608
#define CONV_WG   131072
#define CONV_WOUT 32768
#define CONV_TOTAL (CONV_WIN + CONV_WG + CONV_WOUT)   // 360448

typedef __attribute__((ext_vector_type(4))) float f32x4;
typedef __attribute__((ext_vector_type(8))) short bf16x8;
typedef __attribute__((ext_vector_type(8))) unsigned short u16x8;

static __device__ __forceinline__ unsigned short f2bf(float f) {
    __hip_bfloat16 h = __float2bfloat16(f);
    return *reinterpret_cast<unsigned short*>(&h);
}
static __device__ __forceinline__ float bf2f(unsigned short u) {
    return __uint_as_float((unsigned)u << 16);
}

// ---------------- workspace layout (bytes) ----------------
#define OFF_H0     (0u)                          // 4MB f32
#define OFF_H1     (4u<<20)                      // 4MB f32
#define OFF_HH     (8u<<20)                      // 2MB bf16
#define OFF_SPART  (10u<<20)                     // 128*256*4 = 131072
#define OFF_SSRC   (OFF_SPART + 131072u)         // 65536
#define OFF_SDST   (OFF_SSRC + 65536u)           // 65536
#define OFF_WINT   (OFF_SDST + 65536u)           // 393216
#define OFF_WGT    (OFF_WINT + 393216u)          // 262144
#define OFF_WOUTT  (OFF_WGT + 262144u)           // 65536
#define OFF_BM     (OFF_WOUTT + 65536u)          // 2MB

struct SharedMem {
    unsigned short As[32][72];
    unsigned short Bs[64][72];
    float sredS[4][32];
    float sredD[4][32];
    int   csr[DEGCAP];
    float w[4*DEGCAP];
    int   cnt;
    int   flag;
};

// ---------------- weight transpose+convert, one element ----------------
static __device__ __forceinline__ void convert_one(
    int d, const float* __restrict__ Win, const float* __restrict__ Wg,
    const float* __restrict__ Wout, unsigned short* __restrict__ WinT,
    unsigned short* __restrict__ WgT, unsigned short* __restrict__ WoutT)
{
    if (d < CONV_WIN) {                       // WinT[c][k] = Win[k][c]
        int c = d / 768, k = d - c*768;
        WinT[d] = f2bf(Win[(size_t)k*256 + c]);
    } else if (d < CONV_WIN + CONV_WG) {      // WgT[m][o][i] = Wg[m][i][o]
        int e = d - CONV_WIN;
        int m = e >> 14, rem = e & 16383;
        int o = rem >> 8, i = rem & 255;
        WgT[e] = f2bf(Wg[(size_t)m*16384 + i*64 + o]);
    } else {                                  // WoutT[c][k] = Wout[k][c]
        int e = d - (CONV_WIN + CONV_WG);
        int c = e >> 8, k = e & 255;
        WoutT[e] = f2bf(Wout[(size_t)k*128 + c]);
    }
}

// ---------------- MFMA GEMM core (32x64 tile, BK=64, 4 waves) ----------------
static __device__ __forceinline__ void gemm_core(
    const float* __restrict__ A, const unsigned short* __restrict__ BT,
    const float* __restrict__ bias, float* __restrict__ Cf,
    unsigned short* __restrict__ Cb, int N, int K, int relu,
    const float* __restrict__ a_l, float* __restrict__ ssrc,
    float* __restrict__ sdst, float* __restrict__ Spart,
    int bx, int by, int tid, SharedMem* sm)
{
    const int wc = tid >> 6;
    const int lane = tid & 63;
    const int g = lane >> 4, c = lane & 15;
    const int ar = tid >> 3, ak = (tid & 7) * 8;
    const int bc = tid >> 2, bk = (tid & 3) * 16;
    f32x4 acc0 = {0.f,0.f,0.f,0.f}, acc1 = {0.f,0.f,0.f,0.f};
    const float* Arow = A + (size_t)(by*32 + ar)*K;
    const unsigned short* Brow = BT + (size_t)(bx*64 + bc)*K;

    for (int k0 = 0; k0 < K; k0 += 64) {
        float4 av0 = *(const float4*)&Arow[k0 + ak];
        float4 av1 = *(const float4*)&Arow[k0 + ak + 4];
        u16x8 bv0 = *(const u16x8*)&Brow[k0 + bk];
        u16x8 bv1 = *(const u16x8*)&Brow[k0 + bk + 8];
        ushort4 aw0, aw1;
        aw0.x = f2bf(av0.x); aw0.y = f2bf(av0.y); aw0.z = f2bf(av0.z); aw0.w = f2bf(av0.w);
        aw1.x = f2bf(av1.x); aw1.y = f2bf(av1.y); aw1.z = f2bf(av1.z); aw1.w = f2bf(av1.w);
        *(ushort4*)&sm->As[ar][ak]     = aw0;
        *(ushort4*)&sm->As[ar][ak + 4] = aw1;
        *(u16x8*)&sm->Bs[bc][bk]     = bv0;
        *(u16x8*)&sm->Bs[bc][bk + 8] = bv1;
        __syncthreads();
        bf16x8 b0  = *(bf16x8*)&sm->Bs[wc*16 + c][g*8];
        bf16x8 b1  = *(bf16x8*)&sm->Bs[wc*16 + c][32 + g*8];
        bf16x8 a00 = *(bf16x8*)&sm->As[c][g*8];
        bf16x8 a01 = *(bf16x8*)&sm->As[c][32 + g*8];
        bf16x8 a10 = *(bf16x8*)&sm->As[16 + c][g*8];
        bf16x8 a11 = *(bf16x8*)&sm->As[16 + c][32 + g*8];
        acc0 = __builtin_amdgcn_mfma_f32_16x16x32_bf16(a00, b0, acc0, 0, 0, 0);
        acc0 = __builtin_amdgcn_mfma_f32_16x16x32_bf16(a01, b1, acc0, 0, 0, 0);
        acc1 = __builtin_amdgcn_mfma_f32_16x16x32_bf16(a10, b0, acc1, 0, 0, 0);
        acc1 = __builtin_amdgcn_mfma_f32_16x16x32_bf16(a11, b1, acc1, 0, 0, 0);
        __syncthreads();
    }

    const int col = bx*64 + wc*16 + c;
    float bb = bias ? bias[col] : 0.f;
    #pragma unroll
    for (int t = 0; t < 2; ++t) {
        f32x4 av = t ? acc1 : acc0;
        #pragma unroll
        for (int i = 0; i < 4; ++i) {
            int r = by*32 + t*16 + g*4 + i;
            float v = av[i] + bb;
            if (relu) v = fmaxf(v, 0.f);
            if (Cb) Cb[(size_t)r*N + col] = f2bf(v);
            else    Cf[(size_t)r*N + col] = v;
        }
    }

    if (a_l) {
        int h = bx;
        float as = a_l[h*128 + wc*16 + c];
        float ad = a_l[h*128 + 64 + wc*16 + c];
        float ps[8], pd[8], cs = 0.f;
        #pragma unroll
        for (int t = 0; t < 2; ++t) {
            f32x4 av = t ? acc1 : acc0;
            #pragma unroll
            for (int i = 0; i < 4; ++i) {
                ps[t*4+i] = av[i] * as;
                pd[t*4+i] = av[i] * ad;
                cs += av[i];
            }
        }
        #pragma unroll
        for (int off = 1; off < 16; off <<= 1) {
            #pragma unroll
            for (int j = 0; j < 8; ++j) {
                ps[j] += __shfl_xor(ps[j], off);
                pd[j] += __shfl_xor(pd[j], off);
            }
        }
        if (c == 0) {
            #pragma unroll
            for (int t = 0; t < 2; ++t)
                #pragma unroll
                for (int i = 0; i < 4; ++i) {
                    sm->sredS[wc][t*16 + g*4 + i] = ps[t*4+i];
                    sm->sredD[wc][t*16 + g*4 + i] = pd[t*4+i];
                }
        }
        cs += __shfl_xor(cs, 16);
        cs += __shfl_xor(cs, 32);
        if (g == 0)
            Spart[by*256 + col] = cs;
        __syncthreads();
        if (tid < 32) {
            float s1 = sm->sredS[0][tid] + sm->sredS[1][tid] + sm->sredS[2][tid] + sm->sredS[3][tid];
            float s2 = sm->sredD[0][tid] + sm->sredD[1][tid] + sm->sredD[2][tid] + sm->sredD[3][tid];
            int r = by*32 + tid;
            ssrc[r*4 + h] = s1;
            sdst[r*4 + h] = s2;
        }
        __syncthreads();
    }
}

// ---------------- aggregation core (one node per call; Sv = S[tid] inline) ----------------
static __device__ __forceinline__ void aggregate_core(
    const unsigned* __restrict__ bm, const float* __restrict__ ssrc,
    const float* __restrict__ sdst, const unsigned short* __restrict__ hh,
    float Sv, float* __restrict__ hout, int n, int tid, SharedMem* sm)
{
    int h = tid >> 6, o = tid & 63;
    const unsigned* brow = bm + (size_t)n*128;

    if (tid < 64) {
        unsigned wA = brow[2*tid], wB = brow[2*tid + 1];
        int cpc = __popc(wA) + __popc(wB);
        int pre = cpc;
        #pragma unroll
        for (int off = 1; off < 64; off <<= 1) {
            int v = __shfl_up(pre, off);
            if (tid >= off) pre += v;
        }
        int excl = pre - cpc;
        int total = __shfl(pre, 63);
        if (total <= DEGCAP) {
            int pos = excl, base = tid*64;
            unsigned w = wA;
            while (w) { int b = __builtin_ctz(w); sm->csr[pos++] = base + b; w &= w-1; }
            w = wB; base += 32;
            while (w) { int b = __builtin_ctz(w); sm->csr[pos++] = base + b; w &= w-1; }
        }
        if (tid == 0) sm->cnt = total;
    }
    __syncthreads();
    int cnt = sm->cnt;
    float ss = ssrc[n*4 + h];

    if (cnt <= DEGCAP) {
        float mx = 0.f;
        for (int i = o; i < cnt; i += 64) {
            int m = sm->csr[i];
            float e = ss + sdst[m*4 + h];
            e = (e >= 0.f) ? e : 0.2f*e;
            mx = fmaxf(mx, e);
        }
        #pragma unroll
        for (int off = 32; off; off >>= 1) mx = fmaxf(mx, __shfl_xor(mx, off));
        float M = mx;
        float base = expf(-M);

        float zp = 0.f;
        for (int i = o; i < cnt; i += 64) {
            int m = sm->csr[i];
            float e = ss + sdst[m*4 + h];
            e = (e >= 0.f) ? e : 0.2f*e;
            float w = expf(e - M) - base;
            sm->w[h*DEGCAP + i] = w;
            zp += w;
        }
        #pragma unroll
        for (int off = 32; off; off >>= 1) zp += __shfl_xor(zp, off);

        float acc = 0.f;
        int i = 0;
        for (; i + 4 <= cnt; i += 4) {
            int m0 = sm->csr[i],   m1 = sm->csr[i+1];
            int m2 = sm->csr[i+2], m3 = sm->csr[i+3];
            float w0 = sm->w[h*DEGCAP+i],   w1 = sm->w[h*DEGCAP+i+1];
            float w2 = sm->w[h*DEGCAP+i+2], w3 = sm->w[h*DEGCAP+i+3];
            float v0 = bf2f(hh[(size_t)m0*256 + h*64 + o]);
            float v1 = bf2f(hh[(size_t)m1*256 + h*64 + o]);
            float v2 = bf2f(hh[(size_t)m2*256 + h*64 + o]);
            float v3 = bf2f(hh[(size_t)m3*256 + h*64 + o]);
            acc += w0*v0; acc += w1*v1; acc += w2*v2; acc += w3*v3;
        }
        for (; i < cnt; ++i)
            acc += sm->w[h*DEGCAP+i] * bf2f(hh[(size_t)sm->csr[i]*256 + h*64 + o]);

        float Z  = zp + (float)NNODES * base;
        float hp = (acc + base * Sv) / Z;
        hout[(size_t)n*256 + tid] = fmaxf(hp, 0.f);
    } else {
        float mx = 0.f;
        for (int m = o; m < NNODES; m += 64) {
            if ((brow[m>>5] >> (m & 31)) & 1u) {
                float e = ss + sdst[m*4 + h];
                e = (e >= 0.f) ? e : 0.2f*e;
                mx = fmaxf(mx, e);
            }
        }
        #pragma unroll
        for (int off = 32; off; off >>= 1) mx = fmaxf(mx, __shfl_xor(mx, off));
        float M = mx;
        float base = expf(-M);
        float zp = 0.f, acc = 0.f;
        for (int m = 0; m < NNODES; ++m) {
            if ((brow[m>>5] >> (m & 31)) & 1u) {
                float e = ss + sdst[m*4 + h];
                e = (e >= 0.f) ? e : 0.2f*e;
                float w = expf(e - M) - base;
                zp += w;
                acc += w * bf2f(hh[(size_t)m*256 + h*64 + o]);
            }
        }
        float Z  = zp + (float)NNODES * base;
        float hp = (acc + base * Sv) / Z;
        hout[(size_t)n*256 + tid] = fmaxf(hp, 0.f);
    }
    __syncthreads();   // protect sm->csr/w before next node
}

// ---------------- edge phase body (shared by mega + fallback) ----------------
static __device__ __forceinline__ void edge_phase(
    const int* __restrict__ ei, unsigned* __restrict__ bm,
    const float* Win, const float* Wg, const float* Wout,
    unsigned short* WinT, unsigned short* WgT, unsigned short* WoutT,
    int bid, int tid, SharedMem* sm)
{
    if (tid < 64) {
        int v = ei[2*tid + 1];
        unsigned long long ball = __ballot(v == 0);
        if (tid == 0) sm->flag = (ball == ~0ull) ? 1 : 0;
    }
    __syncthreads();
    int is64 = sm->flag;
    int k = bid*256 + tid;                       // exactly NEDGES threads
    int r = is64 ? ei[2*k]            : ei[k];
    int c = is64 ? ei[2*NEDGES + 2*k] : ei[NEDGES + k];
    r &= (NNODES-1); c &= (NNODES-1);
    atomicOr(&bm[(size_t)r*128 + (c>>5)], 1u << (c & 31));
    for (int d = bid*256 + tid; d < CONV_TOTAL; d += NBLK*256)
        convert_one(d, Win, Wg, Wout, WinT, WgT, WoutT);
}

// ================= cooperative mega-kernel: whole model, 1 dispatch =================
__global__ __launch_bounds__(256) void mega(
    const float* __restrict__ x, const int* __restrict__ ei,
    const float* __restrict__ Win, const float* __restrict__ bin_,
    const float* __restrict__ Wg, const float* __restrict__ a,
    const float* __restrict__ Wout, const float* __restrict__ bout,
    float* __restrict__ out,
    float* __restrict__ h0, float* __restrict__ h1,
    unsigned short* __restrict__ hh, float* __restrict__ Spart,
    float* __restrict__ ssrc, float* __restrict__ sdst,
    unsigned short* __restrict__ WinT, unsigned short* __restrict__ WgT,
    unsigned short* __restrict__ WoutT, unsigned* __restrict__ bm)
{
    cg::grid_group grid = cg::this_grid();
    __shared__ SharedMem sm;
    const int bid = blockIdx.x, tid = threadIdx.x;

    // P0: zero bitmap (512*256 uint4 = 2MB exactly)
    ((uint4*)bm)[bid*256 + tid] = make_uint4(0u,0u,0u,0u);
    grid.sync();

    // P1: adjacency bitmap + weight transpose/convert (independent)
    edge_phase(ei, bm, Win, Wg, Wout, WinT, WgT, WoutT, bid, tid, &sm);
    grid.sync();

    // P2: h0 = relu(x @ Win + bin)   grid (4,128) == 512 blocks
    gemm_core(x, WinT, bin_, h0, nullptr, D_H, D_IN, 1,
              nullptr, nullptr, nullptr, nullptr, bid & 3, bid >> 2, tid, &sm);
    grid.sync();

    float* hin = h0;
    float* hcur = h1;
    for (int l = 0; l < 2; ++l) {
        // hh = hin @ Wg[l]  (+ scores, Spart)
        gemm_core(hin, WgT + (size_t)l*NHEAD*D_HEAD*D_H, nullptr, nullptr, hh,
                  D_H, D_H, 0, a + (size_t)l*NHEAD*128, ssrc, sdst, Spart,
                  bid & 3, bid >> 2, tid, &sm);
        grid.sync();

        // aggregate: 8 nodes per block; S[tid] summed inline (order b=0..127)
        float Sv = 0.f;
        for (int b = 0; b < 128; ++b) Sv += Spart[b*256 + tid];
        for (int v = 0; v < 8; ++v)
            aggregate_core(bm, ssrc, sdst, hh, Sv, hcur, v*NBLK + bid, tid, &sm);
        grid.sync();

        float* t = hin; hin = hcur; hcur = t;
    }

    // P7: out = hin @ Wout + bout   grid (2,128) == 256 blocks
    if (bid < 256)
        gemm_core(hin, WoutT, bout, out, nullptr, D_OUT, D_H, 0,
                  nullptr, nullptr, nullptr, nullptr, bid & 1, bid >> 1, tid, &sm);
}

// ================= fallback multi-kernel path =================
__global__ __launch_bounds__(256) void k_zero_bm(uint4* __restrict__ bm4)
{
    bm4[blockIdx.x*256 + threadIdx.x] = make_uint4(0u,0u,0u,0u);
}

__global__ __launch_bounds__(256) void k_prep(
    const int* __restrict__ ei, unsigned* __restrict__ bm,
    const float* Win, const float* Wg, const float* Wout,
    unsigned short* WinT, unsigned short* WgT, unsigned short* WoutT)
{
    __shared__ SharedMem sm;
    edge_phase(ei, bm, Win, Wg, Wout, WinT, WgT, WoutT, blockIdx.x, threadIdx.x, &sm);
}

__global__ __launch_bounds__(256) void k_gemm(
    const float* __restrict__ A, const unsigned short* __restrict__ BT,
    const float* __restrict__ bias, float* __restrict__ Cf,
    unsigned short* __restrict__ Cb, int N, int K, int relu,
    const float* __restrict__ a_l, float* __restrict__ ssrc,
    float* __restrict__ sdst, float* __restrict__ Spart)
{
    __shared__ SharedMem sm;
    gemm_core(A, BT, bias, Cf, Cb, N, K, relu, a_l, ssrc, sdst, Spart,
              blockIdx.x, blockIdx.y, threadIdx.x, &sm);
}

__global__ __launch_bounds__(256) void k_agg(
    const unsigned* __restrict__ bm, const float* __restrict__ ssrc,
    const float* __restrict__ sdst, const unsigned short* __restrict__ hh,
    const float* __restrict__ Spart, float* __restrict__ hout)
{
    __shared__ SharedMem sm;
    int tid = threadIdx.x;
    float Sv = 0.f;
    for (int b = 0; b < 128; ++b) Sv += Spart[b*256 + tid];
    for (int v = 0; v < 8; ++v)
        aggregate_core(bm, ssrc, sdst, hh, Sv, hout, v*NBLK + blockIdx.x, tid, &sm);
}

// ---------------- host ----------------
static int find_size(const int* sz, int n, int want, int fallback)
{
    for (int i = 0; i < n; ++i) if (sz[i] == want) return i;
    return fallback;
}

extern "C" void kernel_launch(void* const* d_in, const int* in_sizes, int n_in,
                              void* d_out, int out_size, void* d_ws, size_t ws_size,
                              hipStream_t stream)
{
    int ix   = find_size(in_sizes, n_in, NNODES*D_IN, 0);
    int ie   = find_size(in_sizes, n_in, 2*NEDGES, 1);
    int iwin = find_size(in_sizes, n_in, D_IN*D_H, 2);
    int ibin = find_size(in_sizes, n_in, D_H, 3);
    int iwg  = find_size(in_sizes, n_in, 2*NHEAD*D_H*D_HEAD, 4);
    int ia   = find_size(in_sizes, n_in, 2*NHEAD*2*D_HEAD, 5);
    int iwo  = find_size(in_sizes, n_in, D_H*D_OUT, 6);
    int ibo  = find_size(in_sizes, n_in, D_OUT, 7);

    const float* x    = (const float*)d_in[ix];
    const int*   ei   = (const int*)d_in[ie];
    const float* Win  = (const float*)d_in[iwin];
    const float* bin_ = (const float*)d_in[ibin];
    const float* Wg   = (const float*)d_in[iwg];
    const float* a    = (const float*)d_in[ia];
    const float* Wout = (const float*)d_in[iwo];
    const float* bout = (const float*)d_in[ibo];
    float* out = (float*)d_out;

    char* ws = (char*)d_ws;
    float*          h0    = (float*)(ws + OFF_H0);
    float*          h1    = (float*)(ws + OFF_H1);
    unsigned short* hh    = (unsigned short*)(ws + OFF_HH);
    float*          Spart = (float*)(ws + OFF_SPART);
    float*          ssrc  = (float*)(ws + OFF_SSRC);
    float*          sdst  = (float*)(ws + OFF_SDST);
    unsigned short* WinT  = (unsigned short*)(ws + OFF_WINT);
    unsigned short* WgT   = (unsigned short*)(ws + OFF_WGT);
    unsigned short* WoutT = (unsigned short*)(ws + OFF_WOUTT);
    unsigned*       bm    = (unsigned*)(ws + OFF_BM);

    void* args[] = {
        (void*)&x, (void*)&ei, (void*)&Win, (void*)&bin_, (void*)&Wg,
        (void*)&a, (void*)&Wout, (void*)&bout, (void*)&out,
        (void*)&h0, (void*)&h1, (void*)&hh, (void*)&Spart,
        (void*)&ssrc, (void*)&sdst, (void*)&WinT, (void*)&WgT,
        (void*)&WoutT, (void*)&bm
    };
    hipError_t err = hipLaunchCooperativeKernel((void*)mega, dim3(NBLK), dim3(256),
                                                args, 0, stream);
    if (err == hipSuccess) return;

    // -------- fallback: 8-dispatch path (same cores) --------
    k_zero_bm<<<NBLK, 256, 0, stream>>>((uint4*)bm);
    k_prep<<<NBLK, 256, 0, stream>>>(ei, bm, Win, Wg, Wout, WinT, WgT, WoutT);
    {
        dim3 g(D_H/64, NNODES/32);
        k_gemm<<<g, 256, 0, stream>>>(x, WinT, bin_, h0, nullptr, D_H, D_IN, 1,
                                      nullptr, nullptr, nullptr, nullptr);
    }
    float* hin = h0;
    float* hcur = h1;
    for (int l = 0; l < 2; ++l) {
        dim3 g2(D_H/64, NNODES/32);
        k_gemm<<<g2, 256, 0, stream>>>(hin, WgT + (size_t)l*NHEAD*D_HEAD*D_H,
                                       nullptr, nullptr, hh, D_H, D_H, 0,
                                       a + (size_t)l*NHEAD*128, ssrc, sdst, Spart);
        k_agg<<<NBLK, 256, 0, stream>>>(bm, ssrc, sdst, hh, Spart, hcur);
        float* t = hin; hin = hcur; hcur = t;
    }
    {
        dim3 g(D_OUT/64, NNODES/32);
        k_gemm<<<g, 256, 0, stream>>>(hin, WoutT, bout, out, nullptr, D_OUT, D_H, 0,
                                      nullptr, nullptr, nullptr, nullptr);
    }
}

// Round 11
// 105.633 us; speedup vs baseline: 5.0589x; 5.0589x over previous
//
#include <hip/hip_runtime.h>
#include <hip/hip_bf16.h>

#define NNODES 4096
#define NEDGES 131072
#define D_IN   768
#define D_H    256
#define NHEAD  4
#define D_HEAD 64
#define D_OUT  128
#define DEGCAP 192
#define CONV_WIN  196608
#define CONV_WG   131072
#define CONV_WOUT 32768
#define CONV_TOTAL (CONV_WIN + CONV_WG + CONV_WOUT)   // 360448

typedef __attribute__((ext_vector_type(4))) float f32x4;
typedef __attribute__((ext_vector_type(8))) short bf16x8;
typedef __attribute__((ext_vector_type(8))) unsigned short u16x8;

static __device__ __forceinline__ unsigned short f2bf(float f) {
    __hip_bfloat16 h = __float2bfloat16(f);
    return *reinterpret_cast<unsigned short*>(&h);
}
static __device__ __forceinline__ float bf2f(unsigned short u) {
    return __uint_as_float((unsigned)u << 16);
}

// ---------------- workspace layout (bytes) ----------------
#define OFF_H0     (0u)                          // 4MB f32
#define OFF_H1     (4u<<20)                      // 4MB f32
#define OFF_HH     (8u<<20)                      // 2MB bf16
#define OFF_SPART  (10u<<20)                     // 128*256*4 = 131072
#define OFF_SSRC   (OFF_SPART + 131072u)         // 65536
#define OFF_SDST   (OFF_SSRC + 65536u)           // 65536
#define OFF_WINT   (OFF_SDST + 65536u)           // 393216
#define OFF_WGT    (OFF_WINT + 393216u)          // 262144
#define OFF_WOUTT  (OFF_WGT + 262144u)           // 65536
#define OFF_BM     (OFF_WOUTT + 65536u)          // 2MB

struct GemmShared {
    unsigned short As[32][72];
    unsigned short Bs[64][72];
    float sredS[4][32];
    float sredD[4][32];
};

// ---------------- bitmap zero ----------------
__global__ __launch_bounds__(256) void k_zero_bm(uint4* __restrict__ bm4)
{
    bm4[blockIdx.x*256 + threadIdx.x] = make_uint4(0u,0u,0u,0u);
}

// ---------------- adjacency bitmap + weight convert (fused) ----------------
__global__ __launch_bounds__(256) void k_prep(
    const int* __restrict__ ei, unsigned* __restrict__ bm,
    const float* __restrict__ Win, const float* __restrict__ Wg,
    const float* __restrict__ Wout,
    unsigned short* __restrict__ WinT, unsigned short* __restrict__ WgT,
    unsigned short* __restrict__ WoutT)
{
    __shared__ int flag;
    int tid = threadIdx.x, bid = blockIdx.x;
    if (tid < 64) {
        int v = ei[2*tid + 1];
        unsigned long long ball = __ballot(v == 0);
        if (tid == 0) flag = (ball == ~0ull) ? 1 : 0;
    }
    __syncthreads();
    int is64 = flag;
    int k = bid*256 + tid;                       // exactly NEDGES threads
    int r = is64 ? ei[2*k]            : ei[k];
    int c = is64 ? ei[2*NEDGES + 2*k] : ei[NEDGES + k];
    r &= (NNODES-1); c &= (NNODES-1);
    atomicOr(&bm[(size_t)r*128 + (c>>5)], 1u << (c & 31));

    for (int d = bid*256 + tid; d < CONV_TOTAL; d += 512*256) {
        if (d < CONV_WIN) {                       // WinT[c][k] = Win[k][c]
            int cc = d / 768, kk = d - cc*768;
            WinT[d] = f2bf(Win[(size_t)kk*256 + cc]);
        } else if (d < CONV_WIN + CONV_WG) {      // WgT[m][o][i] = Wg[m][i][o]
            int e = d - CONV_WIN;
            int m = e >> 14, rem = e & 16383;
            int o = rem >> 8, i = rem & 255;
            WgT[e] = f2bf(Wg[(size_t)m*16384 + i*64 + o]);
        } else {                                  // WoutT[c][k] = Wout[k][c]
            int e = d - (CONV_WIN + CONV_WG);
            int cc = e >> 8, kk = e & 255;
            WoutT[e] = f2bf(Wout[(size_t)kk*128 + cc]);
        }
    }
}

// ---------------- MFMA GEMM (32x64 tile, BK=64, 4 waves, XCD-swizzled) ----------------
// bid = xcd + 8*(bx + nbx*byg), by = byg*8 + xcd: the nbx blocks sharing an
// A-row-panel land on the SAME XCD -> panel fetched once per XCD L2.
__global__ __launch_bounds__(256) void k_gemm(
    const float* __restrict__ A, const unsigned short* __restrict__ BT,
    const float* __restrict__ bias, float* __restrict__ Cf,
    unsigned short* __restrict__ Cb, int N, int K, int relu, int nbx,
    const float* __restrict__ a_l, float* __restrict__ ssrc,
    float* __restrict__ sdst, float* __restrict__ Spart)
{
    __shared__ GemmShared sm;
    const int bid = blockIdx.x;
    const int xcd = bid & 7, q = bid >> 3;
    const int bx = q % nbx;
    const int by = (q / nbx)*8 + xcd;
    const int tid = threadIdx.x;
    const int wc = tid >> 6;
    const int lane = tid & 63;
    const int g = lane >> 4, c = lane & 15;
    const int ar = tid >> 3, ak = (tid & 7) * 8;
    const int bc = tid >> 2, bk = (tid & 3) * 16;
    f32x4 acc0 = {0.f,0.f,0.f,0.f}, acc1 = {0.f,0.f,0.f,0.f};
    const float* Arow = A + (size_t)(by*32 + ar)*K;
    const unsigned short* Brow = BT + (size_t)(bx*64 + bc)*K;

    for (int k0 = 0; k0 < K; k0 += 64) {
        float4 av0 = *(const float4*)&Arow[k0 + ak];
        float4 av1 = *(const float4*)&Arow[k0 + ak + 4];
        u16x8 bv0 = *(const u16x8*)&Brow[k0 + bk];
        u16x8 bv1 = *(const u16x8*)&Brow[k0 + bk + 8];
        ushort4 aw0, aw1;
        aw0.x = f2bf(av0.x); aw0.y = f2bf(av0.y); aw0.z = f2bf(av0.z); aw0.w = f2bf(av0.w);
        aw1.x = f2bf(av1.x); aw1.y = f2bf(av1.y); aw1.z = f2bf(av1.z); aw1.w = f2bf(av1.w);
        *(ushort4*)&sm.As[ar][ak]     = aw0;
        *(ushort4*)&sm.As[ar][ak + 4] = aw1;
        *(u16x8*)&sm.Bs[bc][bk]     = bv0;
        *(u16x8*)&sm.Bs[bc][bk + 8] = bv1;
        __syncthreads();
        bf16x8 b0  = *(bf16x8*)&sm.Bs[wc*16 + c][g*8];
        bf16x8 b1  = *(bf16x8*)&sm.Bs[wc*16 + c][32 + g*8];
        bf16x8 a00 = *(bf16x8*)&sm.As[c][g*8];
        bf16x8 a01 = *(bf16x8*)&sm.As[c][32 + g*8];
        bf16x8 a10 = *(bf16x8*)&sm.As[16 + c][g*8];
        bf16x8 a11 = *(bf16x8*)&sm.As[16 + c][32 + g*8];
        acc0 = __builtin_amdgcn_mfma_f32_16x16x32_bf16(a00, b0, acc0, 0, 0, 0);
        acc0 = __builtin_amdgcn_mfma_f32_16x16x32_bf16(a01, b1, acc0, 0, 0, 0);
        acc1 = __builtin_amdgcn_mfma_f32_16x16x32_bf16(a10, b0, acc1, 0, 0, 0);
        acc1 = __builtin_amdgcn_mfma_f32_16x16x32_bf16(a11, b1, acc1, 0, 0, 0);
        __syncthreads();
    }

    const int col = bx*64 + wc*16 + c;
    float bb = bias ? bias[col] : 0.f;
    #pragma unroll
    for (int t = 0; t < 2; ++t) {
        f32x4 av = t ? acc1 : acc0;
        #pragma unroll
        for (int i = 0; i < 4; ++i) {
            int r = by*32 + t*16 + g*4 + i;
            float v = av[i] + bb;
            if (relu) v = fmaxf(v, 0.f);
            if (Cb) Cb[(size_t)r*N + col] = f2bf(v);
            else    Cf[(size_t)r*N + col] = v;
        }
    }

    if (a_l) {
        int h = bx;
        float as = a_l[h*128 + wc*16 + c];
        float ad = a_l[h*128 + 64 + wc*16 + c];
        float ps[8], pd[8], cs = 0.f;
        #pragma unroll
        for (int t = 0; t < 2; ++t) {
            f32x4 av = t ? acc1 : acc0;
            #pragma unroll
            for (int i = 0; i < 4; ++i) {
                ps[t*4+i] = av[i] * as;
                pd[t*4+i] = av[i] * ad;
                cs += av[i];
            }
        }
        #pragma unroll
        for (int off = 1; off < 16; off <<= 1) {
            #pragma unroll
            for (int j = 0; j < 8; ++j) {
                ps[j] += __shfl_xor(ps[j], off);
                pd[j] += __shfl_xor(pd[j], off);
            }
        }
        if (c == 0) {
            #pragma unroll
            for (int t = 0; t < 2; ++t)
                #pragma unroll
                for (int i = 0; i < 4; ++i) {
                    sm.sredS[wc][t*16 + g*4 + i] = ps[t*4+i];
                    sm.sredD[wc][t*16 + g*4 + i] = pd[t*4+i];
                }
        }
        cs += __shfl_xor(cs, 16);
        cs += __shfl_xor(cs, 32);
        if (g == 0)
            Spart[by*256 + col] = cs;
        __syncthreads();
        if (tid < 32) {
            float s1 = sm.sredS[0][tid] + sm.sredS[1][tid] + sm.sredS[2][tid] + sm.sredS[3][tid];
            float s2 = sm.sredD[0][tid] + sm.sredD[1][tid] + sm.sredD[2][tid] + sm.sredD[3][tid];
            int r = by*32 + tid;
            ssrc[r*4 + h] = s1;
            sdst[r*4 + h] = s2;
        }
    }
}

// ---------------- aggregation: 1024 blocks x 4 nodes; S[tid] summed inline ----------------
// Exact dense-softmax identity:
//   M = max(0, max_e e); base = exp(-M)
//   Z = sum_edges(exp(e-M)-base) + N*base
//   hp = [ sum_edges (exp(e-M)-base)*hh[m] + base*S ] / Z
__global__ __launch_bounds__(256) void k_agg(
    const unsigned* __restrict__ bm, const float* __restrict__ ssrc,
    const float* __restrict__ sdst, const unsigned short* __restrict__ hh,
    const float* __restrict__ Spart, float* __restrict__ hout)
{
    __shared__ int   csr[DEGCAP];
    __shared__ float wl[4*DEGCAP];
    __shared__ int   cnt_sh;
    const int tid = threadIdx.x;
    const int h = tid >> 6, o = tid & 63;

    float Sv = 0.f;
    for (int b = 0; b < 128; ++b) Sv += Spart[b*256 + tid];   // order matches colsum2

    for (int v = 0; v < 4; ++v) {
        int n = v*1024 + blockIdx.x;
        const unsigned* brow = bm + (size_t)n*128;

        if (tid < 64) {
            unsigned wA = brow[2*tid], wB = brow[2*tid + 1];
            int cpc = __popc(wA) + __popc(wB);
            int pre = cpc;
            #pragma unroll
            for (int off = 1; off < 64; off <<= 1) {
                int vv = __shfl_up(pre, off);
                if (tid >= off) pre += vv;
            }
            int excl = pre - cpc;
            int total = __shfl(pre, 63);
            if (total <= DEGCAP) {
                int pos = excl, base = tid*64;
                unsigned w = wA;
                while (w) { int b = __builtin_ctz(w); csr[pos++] = base + b; w &= w-1; }
                w = wB; base += 32;
                while (w) { int b = __builtin_ctz(w); csr[pos++] = base + b; w &= w-1; }
            }
            if (tid == 0) cnt_sh = total;
        }
        __syncthreads();
        int cnt = cnt_sh;
        float ss = ssrc[n*4 + h];

        if (cnt <= DEGCAP) {
            float mx = 0.f;
            for (int i = o; i < cnt; i += 64) {
                int m = csr[i];
                float e = ss + sdst[m*4 + h];
                e = (e >= 0.f) ? e : 0.2f*e;
                mx = fmaxf(mx, e);
            }
            #pragma unroll
            for (int off = 32; off; off >>= 1) mx = fmaxf(mx, __shfl_xor(mx, off));
            float M = mx;
            float base = expf(-M);

            float zp = 0.f;
            for (int i = o; i < cnt; i += 64) {
                int m = csr[i];
                float e = ss + sdst[m*4 + h];
                e = (e >= 0.f) ? e : 0.2f*e;
                float w = expf(e - M) - base;
                wl[h*DEGCAP + i] = w;
                zp += w;
            }
            #pragma unroll
            for (int off = 32; off; off >>= 1) zp += __shfl_xor(zp, off);

            float acc = 0.f;
            int i = 0;
            for (; i + 4 <= cnt; i += 4) {
                int m0 = csr[i],   m1 = csr[i+1];
                int m2 = csr[i+2], m3 = csr[i+3];
                float w0 = wl[h*DEGCAP+i],   w1 = wl[h*DEGCAP+i+1];
                float w2 = wl[h*DEGCAP+i+2], w3 = wl[h*DEGCAP+i+3];
                float v0 = bf2f(hh[(size_t)m0*256 + h*64 + o]);
                float v1 = bf2f(hh[(size_t)m1*256 + h*64 + o]);
                float v2 = bf2f(hh[(size_t)m2*256 + h*64 + o]);
                float v3 = bf2f(hh[(size_t)m3*256 + h*64 + o]);
                acc += w0*v0; acc += w1*v1; acc += w2*v2; acc += w3*v3;
            }
            for (; i < cnt; ++i)
                acc += wl[h*DEGCAP+i] * bf2f(hh[(size_t)csr[i]*256 + h*64 + o]);

            float Z  = zp + (float)NNODES * base;
            float hp = (acc + base * Sv) / Z;
            hout[(size_t)n*256 + tid] = fmaxf(hp, 0.f);
        } else {
            float mx = 0.f;
            for (int m = o; m < NNODES; m += 64) {
                if ((brow[m>>5] >> (m & 31)) & 1u) {
                    float e = ss + sdst[m*4 + h];
                    e = (e >= 0.f) ? e : 0.2f*e;
                    mx = fmaxf(mx, e);
                }
            }
            #pragma unroll
            for (int off = 32; off; off >>= 1) mx = fmaxf(mx, __shfl_xor(mx, off));
            float M = mx;
            float base = expf(-M);
            float zp = 0.f, acc = 0.f;
            for (int m = 0; m < NNODES; ++m) {
                if ((brow[m>>5] >> (m & 31)) & 1u) {
                    float e = ss + sdst[m*4 + h];
                    e = (e >= 0.f) ? e : 0.2f*e;
                    float w = expf(e - M) - base;
                    zp += w;
                    acc += w * bf2f(hh[(size_t)m*256 + h*64 + o]);
                }
            }
            float Z  = zp + (float)NNODES * base;
            float hp = (acc + base * Sv) / Z;
            hout[(size_t)n*256 + tid] = fmaxf(hp, 0.f);
        }
        __syncthreads();   // protect csr/wl before next node
    }
}

// ---------------- host ----------------
static int find_size(const int* sz, int n, int want, int fallback)
{
    for (int i = 0; i < n; ++i) if (sz[i] == want) return i;
    return fallback;
}

extern "C" void kernel_launch(void* const* d_in, const int* in_sizes, int n_in,
                              void* d_out, int out_size, void* d_ws, size_t ws_size,
                              hipStream_t stream)
{
    int ix   = find_size(in_sizes, n_in, NNODES*D_IN, 0);
    int ie   = find_size(in_sizes, n_in, 2*NEDGES, 1);
    int iwin = find_size(in_sizes, n_in, D_IN*D_H, 2);
    int ibin = find_size(in_sizes, n_in, D_H, 3);
    int iwg  = find_size(in_sizes, n_in, 2*NHEAD*D_H*D_HEAD, 4);
    int ia   = find_size(in_sizes, n_in, 2*NHEAD*2*D_HEAD, 5);
    int iwo  = find_size(in_sizes, n_in, D_H*D_OUT, 6);
    int ibo  = find_size(in_sizes, n_in, D_OUT, 7);

    const float* x    = (const float*)d_in[ix];
    const int*   ei   = (const int*)d_in[ie];
    const float* Win  = (const float*)d_in[iwin];
    const float* bin_ = (const float*)d_in[ibin];
    const float* Wg   = (const float*)d_in[iwg];
    const float* a    = (const float*)d_in[ia];
    const float* Wout = (const float*)d_in[iwo];
    const float* bout = (const float*)d_in[ibo];
    float* out = (float*)d_out;

    char* ws = (char*)d_ws;
    float*          h0    = (float*)(ws + OFF_H0);
    float*          h1    = (float*)(ws + OFF_H1);
    unsigned short* hh    = (unsigned short*)(ws + OFF_HH);
    float*          Spart = (float*)(ws + OFF_SPART);
    float*          ssrc  = (float*)(ws + OFF_SSRC);
    float*          sdst  = (float*)(ws + OFF_SDST);
    unsigned short* WinT  = (unsigned short*)(ws + OFF_WINT);
    unsigned short* WgT   = (unsigned short*)(ws + OFF_WGT);
    unsigned short* WoutT = (unsigned short*)(ws + OFF_WOUTT);
    unsigned*       bm    = (unsigned*)(ws + OFF_BM);

    // d1-d2: bitmap zero -> build + weight convert (layer-invariant)
    k_zero_bm<<<512, 256, 0, stream>>>((uint4*)bm);
    k_prep<<<512, 256, 0, stream>>>(ei, bm, Win, Wg, Wout, WinT, WgT, WoutT);

    // d3: h0 = relu(x @ Win + bin)
    k_gemm<<<512, 256, 0, stream>>>(x, WinT, bin_, h0, nullptr, D_H, D_IN, 1, 4,
                                    nullptr, nullptr, nullptr, nullptr);

    float* hin = h0;
    float* hcur = h1;
    for (int l = 0; l < 2; ++l) {
        // d4/d6: hh = hin @ Wg[l]  (+ scores, Spart)
        k_gemm<<<512, 256, 0, stream>>>(hin, WgT + (size_t)l*NHEAD*D_HEAD*D_H,
                                        nullptr, nullptr, hh, D_H, D_H, 0, 4,
                                        a + (size_t)l*NHEAD*128, ssrc, sdst, Spart);
        // d5/d7: aggregate (S summed inline)
        k_agg<<<1024, 256, 0, stream>>>(bm, ssrc, sdst, hh, Spart, hcur);
        float* t = hin; hin = hcur; hcur = t;
    }

    // d8: out = hin @ Wout + bout
    k_gemm<<<256, 256, 0, stream>>>(hin, WoutT, bout, out, nullptr, D_OUT, D_H, 0, 2,
                                    nullptr, nullptr, nullptr, nullptr);
}